// Round 1
// baseline (10204.552 us; speedup 1.0000x reference)
//
#include <hip/hip_runtime.h>

#define N_USERS 200000
#define N_ITEMS 100000
#define NTOT    300000          // N_USERS + N_ITEMS
#define NNZ     4000000
#define DIM     64
#define TOT_F   (NTOT * DIM)            // 19,200,000 floats
#define TOT_F4  (TOT_F / 4)             // 4,800,000 float4
#define USER_F4 ((N_USERS * DIM) / 4)   // 3,200,000 float4 (clean boundary)

// ---------------------------------------------------------------------------
// Scatter: dst[rows[e]] += vals[e] * src[cols[e]]   (src = ws buffer or the
// virtual concat of the two input embedding tables for layer 1)
// 16 lanes per edge, float4 per lane -> one 256B row per 16-lane group.
// ---------------------------------------------------------------------------
template<bool FROM_INPUTS>
__global__ __launch_bounds__(256) void scatter_kernel(
        const float* __restrict__ vals,
        const int*   __restrict__ rows,
        const int*   __restrict__ cols,
        const float* __restrict__ src,   // used when !FROM_INPUTS
        const float* __restrict__ ue,    // used when FROM_INPUTS
        const float* __restrict__ ie,
        float*       __restrict__ dst)
{
    const int e    = blockIdx.x * (blockDim.x >> 4) + (threadIdx.x >> 4);
    const int lane = threadIdx.x & 15;
    if (e >= NNZ) return;

    const float v = vals[e];
    const int   c = cols[e];
    const int   r = rows[e];

    const float* s;
    if (FROM_INPUTS) {
        s = (c < N_USERS) ? (ue + (size_t)c * DIM)
                          : (ie + (size_t)(c - N_USERS) * DIM);
    } else {
        s = src + (size_t)c * DIM;
    }

    const float4 x = reinterpret_cast<const float4*>(s)[lane];
    float* d = dst + (size_t)r * DIM + (size_t)lane * 4;
    atomicAdd(d + 0, v * x.x);
    atomicAdd(d + 1, v * x.y);
    atomicAdd(d + 2, v * x.z);
    atomicAdd(d + 3, v * x.w);
}

// out = concat(ue, ie) + a        (acc after layer 1: all_emb + emb1)
__global__ __launch_bounds__(256) void acc1_kernel(
        const float* __restrict__ ue, const float* __restrict__ ie,
        const float* __restrict__ a,  float* __restrict__ out)
{
    int i = blockIdx.x * blockDim.x + threadIdx.x;
    if (i >= TOT_F4) return;
    float4 base = (i < USER_F4)
        ? reinterpret_cast<const float4*>(ue)[i]
        : reinterpret_cast<const float4*>(ie)[i - USER_F4];
    float4 av = reinterpret_cast<const float4*>(a)[i];
    float4 o;
    o.x = base.x + av.x; o.y = base.y + av.y;
    o.z = base.z + av.z; o.w = base.w + av.w;
    reinterpret_cast<float4*>(out)[i] = o;
}

// out += b;  z = 0   (accumulate layer-2 result, zero the buffer reused next)
__global__ __launch_bounds__(256) void add_zero_kernel(
        const float* __restrict__ b, float* __restrict__ out,
        float* __restrict__ z)
{
    int i = blockIdx.x * blockDim.x + threadIdx.x;
    if (i >= TOT_F4) return;
    float4 bv = reinterpret_cast<const float4*>(b)[i];
    float4 ov = reinterpret_cast<float4*>(out)[i];
    ov.x += bv.x; ov.y += bv.y; ov.z += bv.z; ov.w += bv.w;
    reinterpret_cast<float4*>(out)[i] = ov;
    reinterpret_cast<float4*>(z)[i] = make_float4(0.f, 0.f, 0.f, 0.f);
}

// out = (out + b) * 0.25
__global__ __launch_bounds__(256) void final_kernel(
        const float* __restrict__ b, float* __restrict__ out)
{
    int i = blockIdx.x * blockDim.x + threadIdx.x;
    if (i >= TOT_F4) return;
    float4 bv = reinterpret_cast<const float4*>(b)[i];
    float4 ov = reinterpret_cast<float4*>(out)[i];
    ov.x = (ov.x + bv.x) * 0.25f; ov.y = (ov.y + bv.y) * 0.25f;
    ov.z = (ov.z + bv.z) * 0.25f; ov.w = (ov.w + bv.w) * 0.25f;
    reinterpret_cast<float4*>(out)[i] = ov;
}

extern "C" void kernel_launch(void* const* d_in, const int* in_sizes, int n_in,
                              void* d_out, int out_size, void* d_ws, size_t ws_size,
                              hipStream_t stream)
{
    const float* ue   = (const float*)d_in[0];   // [200000, 64]
    const float* ie   = (const float*)d_in[1];   // [100000, 64]
    const float* vals = (const float*)d_in[2];   // [NNZ]
    const int*   rows = (const int*)  d_in[3];   // [NNZ]
    const int*   cols = (const int*)  d_in[4];   // [NNZ]
    float* out = (float*)d_out;                  // [NTOT, 64] = users ++ items

    const size_t buf_bytes = (size_t)TOT_F * sizeof(float);   // 76.8 MB
    float* ws0 = (float*)d_ws;
    float* ws1 = (float*)((char*)d_ws + buf_bytes);

    const int eb = 256;                                   // elementwise block
    const int eg = (TOT_F4 + eb - 1) / eb;                // elementwise grid
    const int sb = 256;                                   // scatter block
    const int sg = (NNZ + (sb >> 4) - 1) / (sb >> 4);     // 16 edges / block

    // Layer 1: emb1 = S * all_emb   (read concat directly from inputs)
    hipMemsetAsync(ws0, 0, buf_bytes, stream);
    hipMemsetAsync(ws1, 0, buf_bytes, stream);
    scatter_kernel<true><<<sg, sb, 0, stream>>>(vals, rows, cols,
                                                nullptr, ue, ie, ws0);
    // acc = all_emb + emb1
    acc1_kernel<<<eg, eb, 0, stream>>>(ue, ie, ws0, out);

    // Layer 2: emb2 = S * emb1
    scatter_kernel<false><<<sg, sb, 0, stream>>>(vals, rows, cols,
                                                 ws0, nullptr, nullptr, ws1);
    // acc += emb2; zero ws0 for reuse as layer-3 target
    add_zero_kernel<<<eg, eb, 0, stream>>>(ws1, out, ws0);

    // Layer 3: emb3 = S * emb2
    scatter_kernel<false><<<sg, sb, 0, stream>>>(vals, rows, cols,
                                                 ws1, nullptr, nullptr, ws0);
    // out = (acc + emb3) / 4
    final_kernel<<<eg, eb, 0, stream>>>(ws0, out);
}

// Round 2
// 1263.526 us; speedup vs baseline: 8.0762x; 8.0762x over previous
//
#include <hip/hip_runtime.h>

#define N_USERS 200000
#define N_ITEMS 100000
#define NTOT    300000          // N_USERS + N_ITEMS
#define NNZ     4000000
#define DIM     64
#define TOT_F   (NTOT * DIM)            // 19,200,000 floats
#define TOT_F4  (TOT_F / 4)
#define USER_F4 ((N_USERS * DIM) / 4)

#define SCAN_CHUNK 1024
#define NB_SCAN    ((NTOT + SCAN_CHUNK - 1) / SCAN_CHUNK)   // 293

// ============================ CSR build ====================================

__global__ __launch_bounds__(256) void k_hist(const int* __restrict__ rows,
                                              int* __restrict__ cnt) {
    int i = blockIdx.x * blockDim.x + threadIdx.x;
    if (i < NNZ) atomicAdd(&cnt[rows[i]], 1);
}

// per-1024-chunk sums
__global__ __launch_bounds__(256) void k_block_sum(const int* __restrict__ cnt,
                                                   int* __restrict__ part) {
    __shared__ int lds[256];
    int b = blockIdx.x, t = threadIdx.x;
    int base = b * SCAN_CHUNK + t * 4;
    int s = 0;
#pragma unroll
    for (int k = 0; k < 4; ++k)
        if (base + k < NTOT) s += cnt[base + k];
    lds[t] = s;
    __syncthreads();
    for (int off = 128; off > 0; off >>= 1) {
        if (t < off) lds[t] += lds[t + off];
        __syncthreads();
    }
    if (t == 0) part[b] = lds[0];
}

// serial exclusive scan of the 293 partials (tiny)
__global__ void k_scan_partials(int* part) {
    if (blockIdx.x == 0 && threadIdx.x == 0) {
        int run = 0;
        for (int i = 0; i < NB_SCAN; ++i) {
            int p = part[i];
            part[i] = run;
            run += p;
        }
    }
}

// per-chunk exclusive scan + chunk offset -> rstart, cursor
__global__ __launch_bounds__(256) void k_scan_block(const int* __restrict__ cnt,
                                                    const int* __restrict__ part,
                                                    int* __restrict__ rstart,
                                                    int* __restrict__ cursor) {
    __shared__ int lds[256];
    int b = blockIdx.x, t = threadIdx.x;
    int base = b * SCAN_CHUNK + t * 4;
    int v0 = 0, v1 = 0, v2 = 0, v3 = 0;
    if (base + 0 < NTOT) v0 = cnt[base + 0];
    if (base + 1 < NTOT) v1 = cnt[base + 1];
    if (base + 2 < NTOT) v2 = cnt[base + 2];
    if (base + 3 < NTOT) v3 = cnt[base + 3];
    int s = v0 + v1 + v2 + v3;
    lds[t] = s;
    __syncthreads();
    // Hillis-Steele inclusive scan over 256 thread sums
    for (int off = 1; off < 256; off <<= 1) {
        int x = (t >= off) ? lds[t - off] : 0;
        __syncthreads();
        lds[t] += x;
        __syncthreads();
    }
    int excl = lds[t] - s + part[b];
    int e0 = excl, e1 = e0 + v0, e2 = e1 + v1, e3 = e2 + v2;
    if (base + 0 < NTOT) { rstart[base + 0] = e0; cursor[base + 0] = e0; }
    if (base + 1 < NTOT) { rstart[base + 1] = e1; cursor[base + 1] = e1; }
    if (base + 2 < NTOT) { rstart[base + 2] = e2; cursor[base + 2] = e2; }
    if (base + 3 < NTOT) { rstart[base + 3] = e3; cursor[base + 3] = e3; }
}

__global__ __launch_bounds__(256) void k_permute(const float* __restrict__ vals,
                                                 const int* __restrict__ rows,
                                                 const int* __restrict__ cols,
                                                 int* __restrict__ cursor,
                                                 float* __restrict__ eval,
                                                 int* __restrict__ ecol) {
    int i = blockIdx.x * blockDim.x + threadIdx.x;
    if (i >= NNZ) return;
    int r = rows[i];
    int pos = atomicAdd(&cursor[r], 1);
    eval[pos] = vals[i];
    ecol[pos] = cols[i];
}

// ============================ SpMM (CSR) ===================================
// One wave (64 lanes) per row, lane = dim. No atomics; fused acc epilogue.
// LAYER 1: src = virtual concat(ue,ie); out = base + acc; dst = acc
// LAYER 2: out += acc; dst = acc
// LAYER 3: out = (out + acc) * 0.25   (no dst write)

template<int LAYER>
__device__ __forceinline__ float gsrc(const float* __restrict__ src,
                                      const float* __restrict__ ue,
                                      const float* __restrict__ ie,
                                      int c, int lane) {
    if (LAYER == 1) {
        return (c < N_USERS) ? ue[(size_t)c * DIM + lane]
                             : ie[(size_t)(c - N_USERS) * DIM + lane];
    } else {
        return src[(size_t)c * DIM + lane];
    }
}

template<int LAYER>
__global__ __launch_bounds__(256) void k_spmm(const int* __restrict__ rstart,
                                              const int* __restrict__ cnt,
                                              const float* __restrict__ eval,
                                              const int* __restrict__ ecol,
                                              const float* __restrict__ src,
                                              const float* __restrict__ ue,
                                              const float* __restrict__ ie,
                                              float* __restrict__ dst,
                                              float* __restrict__ out) {
    int wid  = blockIdx.x * 4 + (threadIdx.x >> 6);   // row
    int lane = threadIdx.x & 63;                      // dim
    if (wid >= NTOT) return;
    int start = rstart[wid];
    int end   = start + cnt[wid];

    float acc0 = 0.f, acc1 = 0.f;
    int e = start;
    for (; e + 1 < end; e += 2) {
        float v0 = eval[e],     v1 = eval[e + 1];
        int   c0 = ecol[e],     c1 = ecol[e + 1];
        acc0 += v0 * gsrc<LAYER>(src, ue, ie, c0, lane);
        acc1 += v1 * gsrc<LAYER>(src, ue, ie, c1, lane);
    }
    if (e < end)
        acc0 += eval[e] * gsrc<LAYER>(src, ue, ie, ecol[e], lane);
    float acc = acc0 + acc1;

    size_t o = (size_t)wid * DIM + lane;
    if (LAYER == 1) {
        float base = (wid < N_USERS) ? ue[o] : ie[o - (size_t)N_USERS * DIM];
        out[o] = base + acc;
        dst[o] = acc;
    } else if (LAYER == 2) {
        out[o] += acc;
        dst[o] = acc;
    } else {
        out[o] = (out[o] + acc) * 0.25f;
    }
}

// ===================== fallback (round-1 atomic path) ======================

template<bool FROM_INPUTS>
__global__ __launch_bounds__(256) void scatter_kernel(
        const float* __restrict__ vals, const int* __restrict__ rows,
        const int* __restrict__ cols, const float* __restrict__ src,
        const float* __restrict__ ue, const float* __restrict__ ie,
        float* __restrict__ dst) {
    const int e = blockIdx.x * (blockDim.x >> 4) + (threadIdx.x >> 4);
    const int lane = threadIdx.x & 15;
    if (e >= NNZ) return;
    const float v = vals[e];
    const int c = cols[e];
    const int r = rows[e];
    const float* s = FROM_INPUTS
        ? ((c < N_USERS) ? (ue + (size_t)c * DIM) : (ie + (size_t)(c - N_USERS) * DIM))
        : (src + (size_t)c * DIM);
    const float4 x = reinterpret_cast<const float4*>(s)[lane];
    float* d = dst + (size_t)r * DIM + (size_t)lane * 4;
    atomicAdd(d + 0, v * x.x); atomicAdd(d + 1, v * x.y);
    atomicAdd(d + 2, v * x.z); atomicAdd(d + 3, v * x.w);
}

__global__ __launch_bounds__(256) void acc1_kernel(
        const float* __restrict__ ue, const float* __restrict__ ie,
        const float* __restrict__ a, float* __restrict__ out) {
    int i = blockIdx.x * blockDim.x + threadIdx.x;
    if (i >= TOT_F4) return;
    float4 base = (i < USER_F4)
        ? reinterpret_cast<const float4*>(ue)[i]
        : reinterpret_cast<const float4*>(ie)[i - USER_F4];
    float4 av = reinterpret_cast<const float4*>(a)[i];
    reinterpret_cast<float4*>(out)[i] =
        make_float4(base.x + av.x, base.y + av.y, base.z + av.z, base.w + av.w);
}

__global__ __launch_bounds__(256) void add_zero_kernel(
        const float* __restrict__ b, float* __restrict__ out,
        float* __restrict__ z) {
    int i = blockIdx.x * blockDim.x + threadIdx.x;
    if (i >= TOT_F4) return;
    float4 bv = reinterpret_cast<const float4*>(b)[i];
    float4 ov = reinterpret_cast<float4*>(out)[i];
    reinterpret_cast<float4*>(out)[i] =
        make_float4(ov.x + bv.x, ov.y + bv.y, ov.z + bv.z, ov.w + bv.w);
    reinterpret_cast<float4*>(z)[i] = make_float4(0.f, 0.f, 0.f, 0.f);
}

__global__ __launch_bounds__(256) void final_kernel(
        const float* __restrict__ b, float* __restrict__ out) {
    int i = blockIdx.x * blockDim.x + threadIdx.x;
    if (i >= TOT_F4) return;
    float4 bv = reinterpret_cast<const float4*>(b)[i];
    float4 ov = reinterpret_cast<float4*>(out)[i];
    reinterpret_cast<float4*>(out)[i] =
        make_float4((ov.x + bv.x) * 0.25f, (ov.y + bv.y) * 0.25f,
                    (ov.z + bv.z) * 0.25f, (ov.w + bv.w) * 0.25f);
}

// ===========================================================================

extern "C" void kernel_launch(void* const* d_in, const int* in_sizes, int n_in,
                              void* d_out, int out_size, void* d_ws, size_t ws_size,
                              hipStream_t stream)
{
    const float* ue   = (const float*)d_in[0];
    const float* ie   = (const float*)d_in[1];
    const float* vals = (const float*)d_in[2];
    const int*   rows = (const int*)  d_in[3];
    const int*   cols = (const int*)  d_in[4];
    float* out = (float*)d_out;

    const size_t BUF   = (size_t)TOT_F * sizeof(float);        // 76,800,000
    const size_t O_WS1 = BUF;                                  // 76.8M
    const size_t O_EVAL = 2 * BUF;                             // 153.6M
    const size_t O_ECOL = O_EVAL + (size_t)NNZ * 4;            // 169.6M
    const size_t O_CNT  = O_ECOL + (size_t)NNZ * 4;            // 185.6M
    const size_t O_RST  = O_CNT + (size_t)NTOT * 4;            // 186.8M
    const size_t O_CUR  = O_RST + (size_t)NTOT * 4;            // 188.0M
    const size_t O_PART = O_CUR + (size_t)NTOT * 4;            // 189.2M
    const size_t NEED   = O_PART + 4096;

    float* ws0 = (float*)d_ws;
    float* ws1 = (float*)((char*)d_ws + O_WS1);

    if (ws_size >= NEED) {
        float* eval   = (float*)((char*)d_ws + O_EVAL);
        int*   ecol   = (int*)  ((char*)d_ws + O_ECOL);
        int*   cnt    = (int*)  ((char*)d_ws + O_CNT);
        int*   rstart = (int*)  ((char*)d_ws + O_RST);
        int*   cursor = (int*)  ((char*)d_ws + O_CUR);
        int*   part   = (int*)  ((char*)d_ws + O_PART);

        const int eg = (NNZ + 255) / 256;            // 15625 edge-parallel blocks
        const int sg = (NTOT + 3) / 4;               // 75000 spmm blocks (4 waves)

        hipMemsetAsync(cnt, 0, (size_t)NTOT * 4, stream);
        k_hist<<<eg, 256, 0, stream>>>(rows, cnt);
        k_block_sum<<<NB_SCAN, 256, 0, stream>>>(cnt, part);
        k_scan_partials<<<1, 64, 0, stream>>>(part);
        k_scan_block<<<NB_SCAN, 256, 0, stream>>>(cnt, part, rstart, cursor);
        k_permute<<<eg, 256, 0, stream>>>(vals, rows, cols, cursor, eval, ecol);

        k_spmm<1><<<sg, 256, 0, stream>>>(rstart, cnt, eval, ecol,
                                          nullptr, ue, ie, ws0, out);
        k_spmm<2><<<sg, 256, 0, stream>>>(rstart, cnt, eval, ecol,
                                          ws0, ue, ie, ws1, out);
        k_spmm<3><<<sg, 256, 0, stream>>>(rstart, cnt, eval, ecol,
                                          ws1, ue, ie, nullptr, out);
    } else {
        // fallback: round-1 atomic path (needs only 2*BUF)
        const int eb = 256;
        const int eg2 = (TOT_F4 + eb - 1) / eb;
        const int sg2 = (NNZ + 15) / 16;
        hipMemsetAsync(ws0, 0, BUF, stream);
        hipMemsetAsync(ws1, 0, BUF, stream);
        scatter_kernel<true><<<sg2, 256, 0, stream>>>(vals, rows, cols,
                                                      nullptr, ue, ie, ws0);
        acc1_kernel<<<eg2, eb, 0, stream>>>(ue, ie, ws0, out);
        scatter_kernel<false><<<sg2, 256, 0, stream>>>(vals, rows, cols,
                                                       ws0, nullptr, nullptr, ws1);
        add_zero_kernel<<<eg2, eb, 0, stream>>>(ws1, out, ws0);
        scatter_kernel<false><<<sg2, 256, 0, stream>>>(vals, rows, cols,
                                                       ws1, nullptr, nullptr, ws0);
        final_kernel<<<eg2, eb, 0, stream>>>(ws0, out);
    }
}

// Round 3
// 1242.995 us; speedup vs baseline: 8.2096x; 1.0165x over previous
//
#include <hip/hip_runtime.h>

#define N_USERS 200000
#define N_ITEMS 100000
#define NTOT    300000          // N_USERS + N_ITEMS
#define NNZ     4000000
#define DIM     64
#define TOT_F   (NTOT * DIM)            // 19,200,000 floats
#define TOT_F4  (TOT_F / 4)
#define USER_F4 ((N_USERS * DIM) / 4)

#define SCAN_CHUNK 1024
#define NB_SCAN    ((NTOT + SCAN_CHUNK - 1) / SCAN_CHUNK)   // 293

// ============================ CSR build ====================================

// 4 edges per thread, int4 vectorized (NNZ % 4 == 0)
__global__ __launch_bounds__(256) void k_hist(const int* __restrict__ rows,
                                              int* __restrict__ cnt) {
    int i = blockIdx.x * blockDim.x + threadIdx.x;
    if (i >= NNZ / 4) return;
    int4 r = reinterpret_cast<const int4*>(rows)[i];
    atomicAdd(&cnt[r.x], 1);
    atomicAdd(&cnt[r.y], 1);
    atomicAdd(&cnt[r.z], 1);
    atomicAdd(&cnt[r.w], 1);
}

__global__ __launch_bounds__(256) void k_block_sum(const int* __restrict__ cnt,
                                                   int* __restrict__ part) {
    __shared__ int lds[256];
    int b = blockIdx.x, t = threadIdx.x;
    int base = b * SCAN_CHUNK + t * 4;
    int s = 0;
#pragma unroll
    for (int k = 0; k < 4; ++k)
        if (base + k < NTOT) s += cnt[base + k];
    lds[t] = s;
    __syncthreads();
    for (int off = 128; off > 0; off >>= 1) {
        if (t < off) lds[t] += lds[t + off];
        __syncthreads();
    }
    if (t == 0) part[b] = lds[0];
}

// serial exclusive scan of the 293 partials; also writes the CSR end sentinel
__global__ void k_scan_partials(int* part, int* rstart) {
    if (blockIdx.x == 0 && threadIdx.x == 0) {
        int run = 0;
        for (int i = 0; i < NB_SCAN; ++i) {
            int p = part[i];
            part[i] = run;
            run += p;
        }
        rstart[NTOT] = NNZ;
    }
}

__global__ __launch_bounds__(256) void k_scan_block(const int* __restrict__ cnt,
                                                    const int* __restrict__ part,
                                                    int* __restrict__ rstart,
                                                    int* __restrict__ cursor) {
    __shared__ int lds[256];
    int b = blockIdx.x, t = threadIdx.x;
    int base = b * SCAN_CHUNK + t * 4;
    int v0 = 0, v1 = 0, v2 = 0, v3 = 0;
    if (base + 0 < NTOT) v0 = cnt[base + 0];
    if (base + 1 < NTOT) v1 = cnt[base + 1];
    if (base + 2 < NTOT) v2 = cnt[base + 2];
    if (base + 3 < NTOT) v3 = cnt[base + 3];
    int s = v0 + v1 + v2 + v3;
    lds[t] = s;
    __syncthreads();
    for (int off = 1; off < 256; off <<= 1) {
        int x = (t >= off) ? lds[t - off] : 0;
        __syncthreads();
        lds[t] += x;
        __syncthreads();
    }
    int excl = lds[t] - s + part[b];
    int e0 = excl, e1 = e0 + v0, e2 = e1 + v1, e3 = e2 + v2;
    if (base + 0 < NTOT) { rstart[base + 0] = e0; cursor[base + 0] = e0; }
    if (base + 1 < NTOT) { rstart[base + 1] = e1; cursor[base + 1] = e1; }
    if (base + 2 < NTOT) { rstart[base + 2] = e2; cursor[base + 2] = e2; }
    if (base + 3 < NTOT) { rstart[base + 3] = e3; cursor[base + 3] = e3; }
}

// 4 edges per thread; packs {val,col} into one 8B word per edge
__global__ __launch_bounds__(256) void k_permute(const float* __restrict__ vals,
                                                 const int* __restrict__ rows,
                                                 const int* __restrict__ cols,
                                                 int* __restrict__ cursor,
                                                 long long* __restrict__ ecv) {
    int i = blockIdx.x * blockDim.x + threadIdx.x;
    if (i >= NNZ / 4) return;
    int4   r = reinterpret_cast<const int4*>(rows)[i];
    int4   c = reinterpret_cast<const int4*>(cols)[i];
    float4 v = reinterpret_cast<const float4*>(vals)[i];
#define PUT(RR, CC, VV)                                                  \
    {                                                                    \
        int pos = atomicAdd(&cursor[RR], 1);                             \
        ecv[pos] = ((long long)(unsigned)(CC) << 32) |                   \
                   (unsigned)__float_as_int(VV);                         \
    }
    PUT(r.x, c.x, v.x)
    PUT(r.y, c.y, v.y)
    PUT(r.z, c.z, v.z)
    PUT(r.w, c.w, v.w)
#undef PUT
}

// ============================ SpMM (CSR) ===================================
// One wave per row, lane = dim. 4 independent gathers in flight per wave.

template<int LAYER>
__device__ __forceinline__ float gsrc(const float* __restrict__ src,
                                      const float* __restrict__ ue,
                                      const float* __restrict__ ie,
                                      int c, int lane) {
    if (LAYER == 1) {
        return (c < N_USERS) ? ue[(size_t)c * DIM + lane]
                             : ie[(size_t)(c - N_USERS) * DIM + lane];
    } else {
        return src[(size_t)c * DIM + lane];
    }
}

template<int LAYER>
__global__ __launch_bounds__(256) void k_spmm(const int* __restrict__ rstart,
                                              const long long* __restrict__ ecv,
                                              const float* __restrict__ src,
                                              const float* __restrict__ ue,
                                              const float* __restrict__ ie,
                                              float* __restrict__ dst,
                                              float* __restrict__ out) {
    int wid  = blockIdx.x * 4 + (threadIdx.x >> 6);   // row
    int lane = threadIdx.x & 63;                      // dim
    if (wid >= NTOT) return;
    int start = rstart[wid];
    int end   = rstart[wid + 1];

    float a0 = 0.f, a1 = 0.f, a2 = 0.f, a3 = 0.f;
    int e = start;
    for (; e + 3 < end; e += 4) {
        long long q0 = __builtin_nontemporal_load(ecv + e + 0);
        long long q1 = __builtin_nontemporal_load(ecv + e + 1);
        long long q2 = __builtin_nontemporal_load(ecv + e + 2);
        long long q3 = __builtin_nontemporal_load(ecv + e + 3);
        a0 += __int_as_float((int)q0) * gsrc<LAYER>(src, ue, ie, (int)(q0 >> 32), lane);
        a1 += __int_as_float((int)q1) * gsrc<LAYER>(src, ue, ie, (int)(q1 >> 32), lane);
        a2 += __int_as_float((int)q2) * gsrc<LAYER>(src, ue, ie, (int)(q2 >> 32), lane);
        a3 += __int_as_float((int)q3) * gsrc<LAYER>(src, ue, ie, (int)(q3 >> 32), lane);
    }
    for (; e < end; ++e) {
        long long q = __builtin_nontemporal_load(ecv + e);
        a0 += __int_as_float((int)q) * gsrc<LAYER>(src, ue, ie, (int)(q >> 32), lane);
    }
    float acc = (a0 + a1) + (a2 + a3);

    size_t o = (size_t)wid * DIM + lane;
    if (LAYER == 1) {
        float base = (wid < N_USERS) ? ue[o] : ie[o - (size_t)N_USERS * DIM];
        __builtin_nontemporal_store(base + acc, out + o);
        __builtin_nontemporal_store(acc, dst + o);
    } else if (LAYER == 2) {
        float prev = __builtin_nontemporal_load(out + o);
        __builtin_nontemporal_store(prev + acc, out + o);
        __builtin_nontemporal_store(acc, dst + o);
    } else {
        float prev = __builtin_nontemporal_load(out + o);
        __builtin_nontemporal_store((prev + acc) * 0.25f, out + o);
    }
}

// ===================== fallback (atomic path, small ws) ====================

template<bool FROM_INPUTS>
__global__ __launch_bounds__(256) void scatter_kernel(
        const float* __restrict__ vals, const int* __restrict__ rows,
        const int* __restrict__ cols, const float* __restrict__ src,
        const float* __restrict__ ue, const float* __restrict__ ie,
        float* __restrict__ dst) {
    const int e = blockIdx.x * (blockDim.x >> 4) + (threadIdx.x >> 4);
    const int lane = threadIdx.x & 15;
    if (e >= NNZ) return;
    const float v = vals[e];
    const int c = cols[e];
    const int r = rows[e];
    const float* s = FROM_INPUTS
        ? ((c < N_USERS) ? (ue + (size_t)c * DIM) : (ie + (size_t)(c - N_USERS) * DIM))
        : (src + (size_t)c * DIM);
    const float4 x = reinterpret_cast<const float4*>(s)[lane];
    float* d = dst + (size_t)r * DIM + (size_t)lane * 4;
    atomicAdd(d + 0, v * x.x); atomicAdd(d + 1, v * x.y);
    atomicAdd(d + 2, v * x.z); atomicAdd(d + 3, v * x.w);
}

__global__ __launch_bounds__(256) void acc1_kernel(
        const float* __restrict__ ue, const float* __restrict__ ie,
        const float* __restrict__ a, float* __restrict__ out) {
    int i = blockIdx.x * blockDim.x + threadIdx.x;
    if (i >= TOT_F4) return;
    float4 base = (i < USER_F4)
        ? reinterpret_cast<const float4*>(ue)[i]
        : reinterpret_cast<const float4*>(ie)[i - USER_F4];
    float4 av = reinterpret_cast<const float4*>(a)[i];
    reinterpret_cast<float4*>(out)[i] =
        make_float4(base.x + av.x, base.y + av.y, base.z + av.z, base.w + av.w);
}

__global__ __launch_bounds__(256) void add_zero_kernel(
        const float* __restrict__ b, float* __restrict__ out,
        float* __restrict__ z) {
    int i = blockIdx.x * blockDim.x + threadIdx.x;
    if (i >= TOT_F4) return;
    float4 bv = reinterpret_cast<const float4*>(b)[i];
    float4 ov = reinterpret_cast<float4*>(out)[i];
    reinterpret_cast<float4*>(out)[i] =
        make_float4(ov.x + bv.x, ov.y + bv.y, ov.z + bv.z, ov.w + bv.w);
    reinterpret_cast<float4*>(z)[i] = make_float4(0.f, 0.f, 0.f, 0.f);
}

__global__ __launch_bounds__(256) void final_kernel(
        const float* __restrict__ b, float* __restrict__ out) {
    int i = blockIdx.x * blockDim.x + threadIdx.x;
    if (i >= TOT_F4) return;
    float4 bv = reinterpret_cast<const float4*>(b)[i];
    float4 ov = reinterpret_cast<float4*>(out)[i];
    reinterpret_cast<float4*>(out)[i] =
        make_float4((ov.x + bv.x) * 0.25f, (ov.y + bv.y) * 0.25f,
                    (ov.z + bv.z) * 0.25f, (ov.w + bv.w) * 0.25f);
}

// ===========================================================================

extern "C" void kernel_launch(void* const* d_in, const int* in_sizes, int n_in,
                              void* d_out, int out_size, void* d_ws, size_t ws_size,
                              hipStream_t stream)
{
    const float* ue   = (const float*)d_in[0];
    const float* ie   = (const float*)d_in[1];
    const float* vals = (const float*)d_in[2];
    const int*   rows = (const int*)  d_in[3];
    const int*   cols = (const int*)  d_in[4];
    float* out = (float*)d_out;

    const size_t BUF    = (size_t)TOT_F * sizeof(float);       // 76,800,000
    const size_t O_WS1  = BUF;
    const size_t O_ECV  = 2 * BUF;                             // 153.6M (8B aligned)
    const size_t O_CNT  = O_ECV + (size_t)NNZ * 8;             // 185.6M
    const size_t O_RST  = O_CNT + (size_t)NTOT * 4;
    const size_t O_CUR  = O_RST + (size_t)(NTOT + 1) * 4;
    const size_t O_PART = O_CUR + (size_t)NTOT * 4;
    const size_t NEED   = O_PART + 4096;

    float* ws0 = (float*)d_ws;
    float* ws1 = (float*)((char*)d_ws + O_WS1);

    if (ws_size >= NEED) {
        long long* ecv    = (long long*)((char*)d_ws + O_ECV);
        int*       cnt    = (int*)      ((char*)d_ws + O_CNT);
        int*       rstart = (int*)      ((char*)d_ws + O_RST);
        int*       cursor = (int*)      ((char*)d_ws + O_CUR);
        int*       part   = (int*)      ((char*)d_ws + O_PART);

        const int eg4 = (NNZ / 4 + 255) / 256;       // 4-edges-per-thread grids
        const int sg  = (NTOT + 3) / 4;              // spmm blocks (4 waves)

        hipMemsetAsync(cnt, 0, (size_t)NTOT * 4, stream);
        k_hist<<<eg4, 256, 0, stream>>>(rows, cnt);
        k_block_sum<<<NB_SCAN, 256, 0, stream>>>(cnt, part);
        k_scan_partials<<<1, 64, 0, stream>>>(part, rstart);
        k_scan_block<<<NB_SCAN, 256, 0, stream>>>(cnt, part, rstart, cursor);
        k_permute<<<eg4, 256, 0, stream>>>(vals, rows, cols, cursor, ecv);

        k_spmm<1><<<sg, 256, 0, stream>>>(rstart, ecv, nullptr, ue, ie, ws0, out);
        k_spmm<2><<<sg, 256, 0, stream>>>(rstart, ecv, ws0, ue, ie, ws1, out);
        k_spmm<3><<<sg, 256, 0, stream>>>(rstart, ecv, ws1, ue, ie, nullptr, out);
    } else {
        const int eb = 256;
        const int eg2 = (TOT_F4 + eb - 1) / eb;
        const int sg2 = (NNZ + 15) / 16;
        hipMemsetAsync(ws0, 0, BUF, stream);
        hipMemsetAsync(ws1, 0, BUF, stream);
        scatter_kernel<true><<<sg2, 256, 0, stream>>>(vals, rows, cols,
                                                      nullptr, ue, ie, ws0);
        acc1_kernel<<<eg2, eb, 0, stream>>>(ue, ie, ws0, out);
        scatter_kernel<false><<<sg2, 256, 0, stream>>>(vals, rows, cols,
                                                       ws0, nullptr, nullptr, ws1);
        add_zero_kernel<<<eg2, eb, 0, stream>>>(ws1, out, ws0);
        scatter_kernel<false><<<sg2, 256, 0, stream>>>(vals, rows, cols,
                                                       ws1, nullptr, nullptr, ws0);
        final_kernel<<<eg2, eb, 0, stream>>>(ws0, out);
    }
}

// Round 4
// 993.961 us; speedup vs baseline: 10.2665x; 1.2505x over previous
//
#include <hip/hip_runtime.h>

#define N_USERS 200000
#define N_ITEMS 100000
#define NTOT    300000          // N_USERS + N_ITEMS
#define NNZ     4000000
#define DIM     64
#define TOT_F   (NTOT * DIM)            // 19,200,000 floats
#define TOT_F4  (TOT_F / 4)
#define USER_F4 ((N_USERS * DIM) / 4)

#define SCAN_CHUNK 1024
#define NB_SCAN    ((NTOT + SCAN_CHUNK - 1) / SCAN_CHUNK)   // 293

typedef unsigned short ushort_t;

__device__ __forceinline__ ushort_t f2bf(float f) {
    unsigned u = __float_as_uint(f);
    unsigned r = (u + 0x7FFFu + ((u >> 16) & 1u)) >> 16;   // RNE
    return (ushort_t)r;
}
__device__ __forceinline__ float bf2f(ushort_t b) {
    return __uint_as_float(((unsigned)b) << 16);
}

// ====================== bf16 conversion of concat(ue,ie) ===================
// thread handles 8 floats -> 8 bf16 (16B write)
__global__ __launch_bounds__(256) void k_cvt(const float* __restrict__ ue,
                                             const float* __restrict__ ie,
                                             ushort_t* __restrict__ b0) {
    int i = blockIdx.x * blockDim.x + threadIdx.x;     // 8-float chunk id
    if (i >= TOT_F / 8) return;
    const float4* src = (i < USER_F4 / 2)
        ? reinterpret_cast<const float4*>(ue) + 2 * i
        : reinterpret_cast<const float4*>(ie) + 2 * i - USER_F4;
    float4 a = src[0], b = src[1];
    ushort_t o[8] = { f2bf(a.x), f2bf(a.y), f2bf(a.z), f2bf(a.w),
                      f2bf(b.x), f2bf(b.y), f2bf(b.z), f2bf(b.w) };
    reinterpret_cast<uint4*>(b0)[i] = *reinterpret_cast<uint4*>(o);
}

// ============================ CSR build ====================================

// 4 edges/thread; counts rows AND records each edge's within-row rank
__global__ __launch_bounds__(256) void k_hist(const int* __restrict__ rows,
                                              int* __restrict__ cnt,
                                              int* __restrict__ loff) {
    int i = blockIdx.x * blockDim.x + threadIdx.x;
    if (i >= NNZ / 4) return;
    int4 r = reinterpret_cast<const int4*>(rows)[i];
    int4 o;
    o.x = atomicAdd(&cnt[r.x], 1);
    o.y = atomicAdd(&cnt[r.y], 1);
    o.z = atomicAdd(&cnt[r.z], 1);
    o.w = atomicAdd(&cnt[r.w], 1);
    reinterpret_cast<int4*>(loff)[i] = o;
}

__global__ __launch_bounds__(256) void k_block_sum(const int* __restrict__ cnt,
                                                   int* __restrict__ part) {
    __shared__ int lds[256];
    int b = blockIdx.x, t = threadIdx.x;
    int base = b * SCAN_CHUNK + t * 4;
    int s = 0;
#pragma unroll
    for (int k = 0; k < 4; ++k)
        if (base + k < NTOT) s += cnt[base + k];
    lds[t] = s;
    __syncthreads();
    for (int off = 128; off > 0; off >>= 1) {
        if (t < off) lds[t] += lds[t + off];
        __syncthreads();
    }
    if (t == 0) part[b] = lds[0];
}

__global__ void k_scan_partials(int* part, int* rstart) {
    if (blockIdx.x == 0 && threadIdx.x == 0) {
        int run = 0;
        for (int i = 0; i < NB_SCAN; ++i) {
            int p = part[i];
            part[i] = run;
            run += p;
        }
        rstart[NTOT] = NNZ;
    }
}

__global__ __launch_bounds__(256) void k_scan_block(const int* __restrict__ cnt,
                                                    const int* __restrict__ part,
                                                    int* __restrict__ rstart) {
    __shared__ int lds[256];
    int b = blockIdx.x, t = threadIdx.x;
    int base = b * SCAN_CHUNK + t * 4;
    int v0 = 0, v1 = 0, v2 = 0, v3 = 0;
    if (base + 0 < NTOT) v0 = cnt[base + 0];
    if (base + 1 < NTOT) v1 = cnt[base + 1];
    if (base + 2 < NTOT) v2 = cnt[base + 2];
    if (base + 3 < NTOT) v3 = cnt[base + 3];
    int s = v0 + v1 + v2 + v3;
    lds[t] = s;
    __syncthreads();
    for (int off = 1; off < 256; off <<= 1) {
        int x = (t >= off) ? lds[t - off] : 0;
        __syncthreads();
        lds[t] += x;
        __syncthreads();
    }
    int excl = lds[t] - s + part[b];
    int e0 = excl, e1 = e0 + v0, e2 = e1 + v1, e3 = e2 + v2;
    if (base + 0 < NTOT) rstart[base + 0] = e0;
    if (base + 1 < NTOT) rstart[base + 1] = e1;
    if (base + 2 < NTOT) rstart[base + 2] = e2;
    if (base + 3 < NTOT) rstart[base + 3] = e3;
}

// atomic-free permute: pos = rstart[row] + loff[edge]
__global__ __launch_bounds__(256) void k_permute(const float* __restrict__ vals,
                                                 const int* __restrict__ rows,
                                                 const int* __restrict__ cols,
                                                 const int* __restrict__ rstart,
                                                 const int* __restrict__ loff,
                                                 long long* __restrict__ ecv) {
    int i = blockIdx.x * blockDim.x + threadIdx.x;
    if (i >= NNZ / 4) return;
    int4   r  = reinterpret_cast<const int4*>(rows)[i];
    int4   c  = reinterpret_cast<const int4*>(cols)[i];
    float4 v  = reinterpret_cast<const float4*>(vals)[i];
    int4   lo = reinterpret_cast<const int4*>(loff)[i];
#define PUT(RR, LO, CC, VV)                                              \
    {                                                                    \
        int pos = rstart[RR] + (LO);                                     \
        ecv[pos] = ((long long)(unsigned)(CC) << 32) |                   \
                   (unsigned)__float_as_int(VV);                         \
    }
    PUT(r.x, lo.x, c.x, v.x)
    PUT(r.y, lo.y, c.y, v.y)
    PUT(r.z, lo.z, c.z, v.z)
    PUT(r.w, lo.w, c.w, v.w)
#undef PUT
}

// ============================ SpMM (CSR, bf16 gather) ======================
// One wave per row, lane = dim. 4 independent bf16 row-gathers in flight.
// LAYER 1: out = f32base + acc ; dstb = bf16(acc)
// LAYER 2: out += acc          ; dstb = bf16(acc)
// LAYER 3: out = (out+acc)*0.25

template<int LAYER>
__global__ __launch_bounds__(256) void k_spmm(const int* __restrict__ rstart,
                                              const long long* __restrict__ ecv,
                                              const ushort_t* __restrict__ src,
                                              const float* __restrict__ ue,
                                              const float* __restrict__ ie,
                                              ushort_t* __restrict__ dstb,
                                              float* __restrict__ out) {
    int wid  = blockIdx.x * 4 + (threadIdx.x >> 6);   // row
    int lane = threadIdx.x & 63;                      // dim
    if (wid >= NTOT) return;
    int start = rstart[wid];
    int end   = rstart[wid + 1];

    float a0 = 0.f, a1 = 0.f, a2 = 0.f, a3 = 0.f;
    int e = start;
    for (; e + 3 < end; e += 4) {
        long long q0 = __builtin_nontemporal_load(ecv + e + 0);
        long long q1 = __builtin_nontemporal_load(ecv + e + 1);
        long long q2 = __builtin_nontemporal_load(ecv + e + 2);
        long long q3 = __builtin_nontemporal_load(ecv + e + 3);
        float x0 = bf2f(src[(size_t)(int)(q0 >> 32) * DIM + lane]);
        float x1 = bf2f(src[(size_t)(int)(q1 >> 32) * DIM + lane]);
        float x2 = bf2f(src[(size_t)(int)(q2 >> 32) * DIM + lane]);
        float x3 = bf2f(src[(size_t)(int)(q3 >> 32) * DIM + lane]);
        a0 += __int_as_float((int)q0) * x0;
        a1 += __int_as_float((int)q1) * x1;
        a2 += __int_as_float((int)q2) * x2;
        a3 += __int_as_float((int)q3) * x3;
    }
    for (; e < end; ++e) {
        long long q = __builtin_nontemporal_load(ecv + e);
        a0 += __int_as_float((int)q) * bf2f(src[(size_t)(int)(q >> 32) * DIM + lane]);
    }
    float acc = (a0 + a1) + (a2 + a3);

    size_t o = (size_t)wid * DIM + lane;
    if (LAYER == 1) {
        float base = (wid < N_USERS) ? ue[o] : ie[o - (size_t)N_USERS * DIM];
        __builtin_nontemporal_store(base + acc, out + o);
        dstb[o] = f2bf(acc);
    } else if (LAYER == 2) {
        float prev = __builtin_nontemporal_load(out + o);
        __builtin_nontemporal_store(prev + acc, out + o);
        dstb[o] = f2bf(acc);
    } else {
        float prev = __builtin_nontemporal_load(out + o);
        __builtin_nontemporal_store((prev + acc) * 0.25f, out + o);
    }
}

// ===================== fallback (atomic path, small ws) ====================

template<bool FROM_INPUTS>
__global__ __launch_bounds__(256) void scatter_kernel(
        const float* __restrict__ vals, const int* __restrict__ rows,
        const int* __restrict__ cols, const float* __restrict__ src,
        const float* __restrict__ ue, const float* __restrict__ ie,
        float* __restrict__ dst) {
    const int e = blockIdx.x * (blockDim.x >> 4) + (threadIdx.x >> 4);
    const int lane = threadIdx.x & 15;
    if (e >= NNZ) return;
    const float v = vals[e];
    const int c = cols[e];
    const int r = rows[e];
    const float* s = FROM_INPUTS
        ? ((c < N_USERS) ? (ue + (size_t)c * DIM) : (ie + (size_t)(c - N_USERS) * DIM))
        : (src + (size_t)c * DIM);
    const float4 x = reinterpret_cast<const float4*>(s)[lane];
    float* d = dst + (size_t)r * DIM + (size_t)lane * 4;
    atomicAdd(d + 0, v * x.x); atomicAdd(d + 1, v * x.y);
    atomicAdd(d + 2, v * x.z); atomicAdd(d + 3, v * x.w);
}

__global__ __launch_bounds__(256) void acc1_kernel(
        const float* __restrict__ ue, const float* __restrict__ ie,
        const float* __restrict__ a, float* __restrict__ out) {
    int i = blockIdx.x * blockDim.x + threadIdx.x;
    if (i >= TOT_F4) return;
    float4 base = (i < USER_F4)
        ? reinterpret_cast<const float4*>(ue)[i]
        : reinterpret_cast<const float4*>(ie)[i - USER_F4];
    float4 av = reinterpret_cast<const float4*>(a)[i];
    reinterpret_cast<float4*>(out)[i] =
        make_float4(base.x + av.x, base.y + av.y, base.z + av.z, base.w + av.w);
}

__global__ __launch_bounds__(256) void add_zero_kernel(
        const float* __restrict__ b, float* __restrict__ out,
        float* __restrict__ z) {
    int i = blockIdx.x * blockDim.x + threadIdx.x;
    if (i >= TOT_F4) return;
    float4 bv = reinterpret_cast<const float4*>(b)[i];
    float4 ov = reinterpret_cast<float4*>(out)[i];
    reinterpret_cast<float4*>(out)[i] =
        make_float4(ov.x + bv.x, ov.y + bv.y, ov.z + bv.z, ov.w + bv.w);
    reinterpret_cast<float4*>(z)[i] = make_float4(0.f, 0.f, 0.f, 0.f);
}

__global__ __launch_bounds__(256) void final_kernel(
        const float* __restrict__ b, float* __restrict__ out) {
    int i = blockIdx.x * blockDim.x + threadIdx.x;
    if (i >= TOT_F4) return;
    float4 bv = reinterpret_cast<const float4*>(b)[i];
    float4 ov = reinterpret_cast<float4*>(out)[i];
    reinterpret_cast<float4*>(out)[i] =
        make_float4((ov.x + bv.x) * 0.25f, (ov.y + bv.y) * 0.25f,
                    (ov.z + bv.z) * 0.25f, (ov.w + bv.w) * 0.25f);
}

// ===========================================================================

extern "C" void kernel_launch(void* const* d_in, const int* in_sizes, int n_in,
                              void* d_out, int out_size, void* d_ws, size_t ws_size,
                              hipStream_t stream)
{
    const float* ue   = (const float*)d_in[0];
    const float* ie   = (const float*)d_in[1];
    const float* vals = (const float*)d_in[2];
    const int*   rows = (const int*)  d_in[3];
    const int*   cols = (const int*)  d_in[4];
    float* out = (float*)d_out;

    // bf16 tables: 300000*64*2 = 38,400,000 bytes each
    const size_t BBUF   = (size_t)TOT_F * 2;
    const size_t O_B1   = BBUF;
    const size_t O_B2   = 2 * BBUF;
    const size_t O_ECV  = 3 * BBUF;                       // 115,200,000 (16B aligned)
    const size_t O_LOFF = O_ECV + (size_t)NNZ * 8;        // 147,200,000 (16B aligned)
    const size_t O_CNT  = O_LOFF + (size_t)NNZ * 4;       // 163,200,000
    const size_t O_RST  = O_CNT + (size_t)NTOT * 4;
    const size_t O_PART = O_RST + (size_t)(NTOT + 1) * 4;
    const size_t NEED   = O_PART + 4096;

    if (ws_size >= NEED) {
        ushort_t* b0     = (ushort_t*)d_ws;
        ushort_t* b1     = (ushort_t*)((char*)d_ws + O_B1);
        ushort_t* b2     = (ushort_t*)((char*)d_ws + O_B2);
        long long* ecv   = (long long*)((char*)d_ws + O_ECV);
        int*      loff   = (int*)((char*)d_ws + O_LOFF);
        int*      cnt    = (int*)((char*)d_ws + O_CNT);
        int*      rstart = (int*)((char*)d_ws + O_RST);
        int*      part   = (int*)((char*)d_ws + O_PART);

        const int eg4 = (NNZ / 4 + 255) / 256;       // edge grids, 4 edges/thread
        const int cg  = (TOT_F / 8 + 255) / 256;     // cvt grid, 8 floats/thread
        const int sg  = (NTOT + 3) / 4;              // spmm grid, 4 waves/block

        hipMemsetAsync(cnt, 0, (size_t)NTOT * 4, stream);
        k_cvt<<<cg, 256, 0, stream>>>(ue, ie, b0);
        k_hist<<<eg4, 256, 0, stream>>>(rows, cnt, loff);
        k_block_sum<<<NB_SCAN, 256, 0, stream>>>(cnt, part);
        k_scan_partials<<<1, 64, 0, stream>>>(part, rstart);
        k_scan_block<<<NB_SCAN, 256, 0, stream>>>(cnt, part, rstart);
        k_permute<<<eg4, 256, 0, stream>>>(vals, rows, cols, rstart, loff, ecv);

        k_spmm<1><<<sg, 256, 0, stream>>>(rstart, ecv, b0, ue, ie, b1, out);
        k_spmm<2><<<sg, 256, 0, stream>>>(rstart, ecv, b1, ue, ie, b2, out);
        k_spmm<3><<<sg, 256, 0, stream>>>(rstart, ecv, b2, ue, ie, nullptr, out);
    } else {
        const size_t BUF = (size_t)TOT_F * sizeof(float);
        float* ws0 = (float*)d_ws;
        float* ws1 = (float*)((char*)d_ws + BUF);
        const int eb = 256;
        const int eg2 = (TOT_F4 + eb - 1) / eb;
        const int sg2 = (NNZ + 15) / 16;
        hipMemsetAsync(ws0, 0, BUF, stream);
        hipMemsetAsync(ws1, 0, BUF, stream);
        scatter_kernel<true><<<sg2, 256, 0, stream>>>(vals, rows, cols,
                                                      nullptr, ue, ie, ws0);
        acc1_kernel<<<eg2, eb, 0, stream>>>(ue, ie, ws0, out);
        scatter_kernel<false><<<sg2, 256, 0, stream>>>(vals, rows, cols,
                                                       ws0, nullptr, nullptr, ws1);
        add_zero_kernel<<<eg2, eb, 0, stream>>>(ws1, out, ws0);
        scatter_kernel<false><<<sg2, 256, 0, stream>>>(vals, rows, cols,
                                                       ws1, nullptr, nullptr, ws0);
        final_kernel<<<eg2, eb, 0, stream>>>(ws0, out);
    }
}

// Round 5
// 799.892 us; speedup vs baseline: 12.7574x; 1.2426x over previous
//
#include <hip/hip_runtime.h>

#define N_USERS 200000
#define N_ITEMS 100000
#define NTOT    300000          // N_USERS + N_ITEMS
#define NNZ     4000000
#define DIM     64
#define TOT_F   (NTOT * DIM)            // 19,200,000 floats
#define TOT_F4  (TOT_F / 4)
#define USER_F4 ((N_USERS * DIM) / 4)

#define SCAN_CHUNK 1024
#define NB_SCAN    ((NTOT + SCAN_CHUNK - 1) / SCAN_CHUNK)   // 293

typedef unsigned short ushort_t;

__device__ __forceinline__ ushort_t f2bf(float f) {
    unsigned u = __float_as_uint(f);
    unsigned r = (u + 0x7FFFu + ((u >> 16) & 1u)) >> 16;   // RNE
    return (ushort_t)r;
}
__device__ __forceinline__ float bf2f(ushort_t b) {
    return __uint_as_float(((unsigned)b) << 16);
}

// ====================== bf16 conversion of concat(ue,ie) ===================
__global__ __launch_bounds__(256) void k_cvt(const float* __restrict__ ue,
                                             const float* __restrict__ ie,
                                             ushort_t* __restrict__ b0) {
    int i = blockIdx.x * blockDim.x + threadIdx.x;     // 8-float chunk id
    if (i >= TOT_F / 8) return;
    const float4* src = (i < USER_F4 / 2)
        ? reinterpret_cast<const float4*>(ue) + 2 * i
        : reinterpret_cast<const float4*>(ie) + 2 * i - USER_F4;
    float4 a = src[0], b = src[1];
    ushort_t o[8] = { f2bf(a.x), f2bf(a.y), f2bf(a.z), f2bf(a.w),
                      f2bf(b.x), f2bf(b.y), f2bf(b.z), f2bf(b.w) };
    reinterpret_cast<uint4*>(b0)[i] = *reinterpret_cast<uint4*>(o);
}

// ============================ CSR build ====================================

__global__ __launch_bounds__(256) void k_hist(const int* __restrict__ rows,
                                              int* __restrict__ cnt,
                                              int* __restrict__ loff) {
    int i = blockIdx.x * blockDim.x + threadIdx.x;
    if (i >= NNZ / 4) return;
    int4 r = reinterpret_cast<const int4*>(rows)[i];
    int4 o;
    o.x = atomicAdd(&cnt[r.x], 1);
    o.y = atomicAdd(&cnt[r.y], 1);
    o.z = atomicAdd(&cnt[r.z], 1);
    o.w = atomicAdd(&cnt[r.w], 1);
    reinterpret_cast<int4*>(loff)[i] = o;
}

__global__ __launch_bounds__(256) void k_block_sum(const int* __restrict__ cnt,
                                                   int* __restrict__ part) {
    __shared__ int lds[256];
    int b = blockIdx.x, t = threadIdx.x;
    int base = b * SCAN_CHUNK + t * 4;
    int s = 0;
#pragma unroll
    for (int k = 0; k < 4; ++k)
        if (base + k < NTOT) s += cnt[base + k];
    lds[t] = s;
    __syncthreads();
    for (int off = 128; off > 0; off >>= 1) {
        if (t < off) lds[t] += lds[t + off];
        __syncthreads();
    }
    if (t == 0) part[b] = lds[0];
}

// serial scan of partials; writes CSR sentinel and zero-pads ecv tail
__global__ void k_scan_partials(int* part, int* rstart, long long* ecv) {
    if (blockIdx.x == 0 && threadIdx.x == 0) {
        int run = 0;
        for (int i = 0; i < NB_SCAN; ++i) {
            int p = part[i];
            part[i] = run;
            run += p;
        }
        rstart[NTOT] = NNZ;
        for (int i = 0; i < 16; ++i) ecv[NNZ + i] = 0;   // pad: col=0, val=0
    }
}

__global__ __launch_bounds__(256) void k_scan_block(const int* __restrict__ cnt,
                                                    const int* __restrict__ part,
                                                    int* __restrict__ rstart) {
    __shared__ int lds[256];
    int b = blockIdx.x, t = threadIdx.x;
    int base = b * SCAN_CHUNK + t * 4;
    int v0 = 0, v1 = 0, v2 = 0, v3 = 0;
    if (base + 0 < NTOT) v0 = cnt[base + 0];
    if (base + 1 < NTOT) v1 = cnt[base + 1];
    if (base + 2 < NTOT) v2 = cnt[base + 2];
    if (base + 3 < NTOT) v3 = cnt[base + 3];
    int s = v0 + v1 + v2 + v3;
    lds[t] = s;
    __syncthreads();
    for (int off = 1; off < 256; off <<= 1) {
        int x = (t >= off) ? lds[t - off] : 0;
        __syncthreads();
        lds[t] += x;
        __syncthreads();
    }
    int excl = lds[t] - s + part[b];
    int e0 = excl, e1 = e0 + v0, e2 = e1 + v1, e3 = e2 + v2;
    if (base + 0 < NTOT) rstart[base + 0] = e0;
    if (base + 1 < NTOT) rstart[base + 1] = e1;
    if (base + 2 < NTOT) rstart[base + 2] = e2;
    if (base + 3 < NTOT) rstart[base + 3] = e3;
}

// atomic-free permute: pos = rstart[row] + loff[edge]
__global__ __launch_bounds__(256) void k_permute(const float* __restrict__ vals,
                                                 const int* __restrict__ rows,
                                                 const int* __restrict__ cols,
                                                 const int* __restrict__ rstart,
                                                 const int* __restrict__ loff,
                                                 long long* __restrict__ ecv) {
    int i = blockIdx.x * blockDim.x + threadIdx.x;
    if (i >= NNZ / 4) return;
    int4   r  = reinterpret_cast<const int4*>(rows)[i];
    int4   c  = reinterpret_cast<const int4*>(cols)[i];
    float4 v  = reinterpret_cast<const float4*>(vals)[i];
    int4   lo = reinterpret_cast<const int4*>(loff)[i];
#define PUT(RR, LO, CC, VV)                                              \
    {                                                                    \
        int pos = rstart[RR] + (LO);                                     \
        ecv[pos] = ((long long)(unsigned)(CC) << 32) |                   \
                   (unsigned)__float_as_int(VV);                         \
    }
    PUT(r.x, lo.x, c.x, v.x)
    PUT(r.y, lo.y, c.y, v.y)
    PUT(r.z, lo.z, c.z, v.z)
    PUT(r.w, lo.w, c.w, v.w)
#undef PUT
}

// ============================ SpMM (CSR, bf16 gather) ======================
// One wave per row, lane = dim. Per 16-edge chunk: one coalesced ecv load,
// shfl-broadcast, then 16 independent gathers issued before any FMA.

template<int LAYER>
__global__ __launch_bounds__(256) void k_spmm(const int* __restrict__ rstart,
                                              const long long* __restrict__ ecv,
                                              const ushort_t* __restrict__ src,
                                              const float* __restrict__ ue,
                                              const float* __restrict__ ie,
                                              ushort_t* __restrict__ dstb,
                                              float* __restrict__ out) {
    int wid  = blockIdx.x * 4 + (threadIdx.x >> 6);   // row
    int lane = threadIdx.x & 63;                      // dim
    if (wid >= NTOT) return;
    int start = rstart[wid];
    int end   = rstart[wid + 1];

    float acc = 0.f;
    for (int base = start; base < end; base += 16) {
        // lane l holds edge (l & 15); ecv padded by 16 so this is in-bounds
        long long q = ecv[base + (lane & 15)];
        int rem = end - base;                         // >= 1

        int   cc[16];
        float vv[16];
        int   c0 = 0;
#pragma unroll
        for (int j = 0; j < 16; ++j) {
            long long qq = __shfl(q, j);
            int   c = (int)(qq >> 32);
            float v = __int_as_float((int)(unsigned)(qq & 0xffffffffu));
            if (j == 0) c0 = c;
            bool ok = (j < rem);
            cc[j] = ok ? c : c0;                      // clamp -> same line, L1 hit
            vv[j] = ok ? v : 0.f;
        }
        ushort_t xx[16];
#pragma unroll
        for (int j = 0; j < 16; ++j)                  // 16 independent gathers
            xx[j] = src[(size_t)cc[j] * DIM + lane];
#pragma unroll
        for (int j = 0; j < 16; ++j)
            acc += vv[j] * bf2f(xx[j]);
    }

    size_t o = (size_t)wid * DIM + lane;
    if (LAYER == 1) {
        float basev = (wid < N_USERS) ? ue[o] : ie[o - (size_t)N_USERS * DIM];
        __builtin_nontemporal_store(basev + acc, out + o);
        dstb[o] = f2bf(acc);
    } else if (LAYER == 2) {
        float prev = __builtin_nontemporal_load(out + o);
        __builtin_nontemporal_store(prev + acc, out + o);
        dstb[o] = f2bf(acc);
    } else {
        float prev = __builtin_nontemporal_load(out + o);
        __builtin_nontemporal_store((prev + acc) * 0.25f, out + o);
    }
}

// ===================== fallback (atomic path, small ws) ====================

template<bool FROM_INPUTS>
__global__ __launch_bounds__(256) void scatter_kernel(
        const float* __restrict__ vals, const int* __restrict__ rows,
        const int* __restrict__ cols, const float* __restrict__ src,
        const float* __restrict__ ue, const float* __restrict__ ie,
        float* __restrict__ dst) {
    const int e = blockIdx.x * (blockDim.x >> 4) + (threadIdx.x >> 4);
    const int lane = threadIdx.x & 15;
    if (e >= NNZ) return;
    const float v = vals[e];
    const int c = cols[e];
    const int r = rows[e];
    const float* s = FROM_INPUTS
        ? ((c < N_USERS) ? (ue + (size_t)c * DIM) : (ie + (size_t)(c - N_USERS) * DIM))
        : (src + (size_t)c * DIM);
    const float4 x = reinterpret_cast<const float4*>(s)[lane];
    float* d = dst + (size_t)r * DIM + (size_t)lane * 4;
    atomicAdd(d + 0, v * x.x); atomicAdd(d + 1, v * x.y);
    atomicAdd(d + 2, v * x.z); atomicAdd(d + 3, v * x.w);
}

__global__ __launch_bounds__(256) void acc1_kernel(
        const float* __restrict__ ue, const float* __restrict__ ie,
        const float* __restrict__ a, float* __restrict__ out) {
    int i = blockIdx.x * blockDim.x + threadIdx.x;
    if (i >= TOT_F4) return;
    float4 base = (i < USER_F4)
        ? reinterpret_cast<const float4*>(ue)[i]
        : reinterpret_cast<const float4*>(ie)[i - USER_F4];
    float4 av = reinterpret_cast<const float4*>(a)[i];
    reinterpret_cast<float4*>(out)[i] =
        make_float4(base.x + av.x, base.y + av.y, base.z + av.z, base.w + av.w);
}

__global__ __launch_bounds__(256) void add_zero_kernel(
        const float* __restrict__ b, float* __restrict__ out,
        float* __restrict__ z) {
    int i = blockIdx.x * blockDim.x + threadIdx.x;
    if (i >= TOT_F4) return;
    float4 bv = reinterpret_cast<const float4*>(b)[i];
    float4 ov = reinterpret_cast<float4*>(out)[i];
    reinterpret_cast<float4*>(out)[i] =
        make_float4(ov.x + bv.x, ov.y + bv.y, ov.z + bv.z, ov.w + bv.w);
    reinterpret_cast<float4*>(z)[i] = make_float4(0.f, 0.f, 0.f, 0.f);
}

__global__ __launch_bounds__(256) void final_kernel(
        const float* __restrict__ b, float* __restrict__ out) {
    int i = blockIdx.x * blockDim.x + threadIdx.x;
    if (i >= TOT_F4) return;
    float4 bv = reinterpret_cast<const float4*>(b)[i];
    float4 ov = reinterpret_cast<float4*>(out)[i];
    reinterpret_cast<float4*>(out)[i] =
        make_float4((ov.x + bv.x) * 0.25f, (ov.y + bv.y) * 0.25f,
                    (ov.z + bv.z) * 0.25f, (ov.w + bv.w) * 0.25f);
}

// ===========================================================================

extern "C" void kernel_launch(void* const* d_in, const int* in_sizes, int n_in,
                              void* d_out, int out_size, void* d_ws, size_t ws_size,
                              hipStream_t stream)
{
    const float* ue   = (const float*)d_in[0];
    const float* ie   = (const float*)d_in[1];
    const float* vals = (const float*)d_in[2];
    const int*   rows = (const int*)  d_in[3];
    const int*   cols = (const int*)  d_in[4];
    float* out = (float*)d_out;

    // bf16 tables: 300000*64*2 = 38,400,000 bytes each
    const size_t BBUF   = (size_t)TOT_F * 2;
    const size_t O_B1   = BBUF;
    const size_t O_B2   = 2 * BBUF;
    const size_t O_ECV  = 3 * BBUF;                        // 16B aligned
    const size_t O_LOFF = O_ECV + (size_t)(NNZ + 16) * 8;  // +pad, 16B aligned
    const size_t O_CNT  = O_LOFF + (size_t)NNZ * 4;
    const size_t O_RST  = O_CNT + (size_t)NTOT * 4;
    const size_t O_PART = O_RST + (size_t)(NTOT + 1) * 4;
    const size_t NEED   = O_PART + 4096;

    if (ws_size >= NEED) {
        ushort_t* b0     = (ushort_t*)d_ws;
        ushort_t* b1     = (ushort_t*)((char*)d_ws + O_B1);
        ushort_t* b2     = (ushort_t*)((char*)d_ws + O_B2);
        long long* ecv   = (long long*)((char*)d_ws + O_ECV);
        int*      loff   = (int*)((char*)d_ws + O_LOFF);
        int*      cnt    = (int*)((char*)d_ws + O_CNT);
        int*      rstart = (int*)((char*)d_ws + O_RST);
        int*      part   = (int*)((char*)d_ws + O_PART);

        const int eg4 = (NNZ / 4 + 255) / 256;
        const int cg  = (TOT_F / 8 + 255) / 256;
        const int sg  = (NTOT + 3) / 4;

        hipMemsetAsync(cnt, 0, (size_t)NTOT * 4, stream);
        k_cvt<<<cg, 256, 0, stream>>>(ue, ie, b0);
        k_hist<<<eg4, 256, 0, stream>>>(rows, cnt, loff);
        k_block_sum<<<NB_SCAN, 256, 0, stream>>>(cnt, part);
        k_scan_partials<<<1, 64, 0, stream>>>(part, rstart, ecv);
        k_scan_block<<<NB_SCAN, 256, 0, stream>>>(cnt, part, rstart);
        k_permute<<<eg4, 256, 0, stream>>>(vals, rows, cols, rstart, loff, ecv);

        k_spmm<1><<<sg, 256, 0, stream>>>(rstart, ecv, b0, ue, ie, b1, out);
        k_spmm<2><<<sg, 256, 0, stream>>>(rstart, ecv, b1, ue, ie, b2, out);
        k_spmm<3><<<sg, 256, 0, stream>>>(rstart, ecv, b2, ue, ie, nullptr, out);
    } else {
        const size_t BUF = (size_t)TOT_F * sizeof(float);
        float* ws0 = (float*)d_ws;
        float* ws1 = (float*)((char*)d_ws + BUF);
        const int eb = 256;
        const int eg2 = (TOT_F4 + eb - 1) / eb;
        const int sg2 = (NNZ + 15) / 16;
        hipMemsetAsync(ws0, 0, BUF, stream);
        hipMemsetAsync(ws1, 0, BUF, stream);
        scatter_kernel<true><<<sg2, 256, 0, stream>>>(vals, rows, cols,
                                                      nullptr, ue, ie, ws0);
        acc1_kernel<<<eg2, eb, 0, stream>>>(ue, ie, ws0, out);
        scatter_kernel<false><<<sg2, 256, 0, stream>>>(vals, rows, cols,
                                                       ws0, nullptr, nullptr, ws1);
        add_zero_kernel<<<eg2, eb, 0, stream>>>(ws1, out, ws0);
        scatter_kernel<false><<<sg2, 256, 0, stream>>>(vals, rows, cols,
                                                       ws1, nullptr, nullptr, ws0);
        final_kernel<<<eg2, eb, 0, stream>>>(ws0, out);
    }
}

// Round 7
// 674.046 us; speedup vs baseline: 15.1392x; 1.1867x over previous
//
#include <hip/hip_runtime.h>

#define N_USERS 200000
#define N_ITEMS 100000
#define NTOT    300000          // N_USERS + N_ITEMS
#define NNZ     4000000
#define DIM     64
#define TOT_F   (NTOT * DIM)            // 19,200,000 floats
#define TOT_F4  (TOT_F / 4)
#define USER_F4 ((N_USERS * DIM) / 4)

#define SCAN_CHUNK 1024
#define NB_SCAN    ((NTOT + SCAN_CHUNK - 1) / SCAN_CHUNK)   // 293

typedef unsigned short ushort_t;

__device__ __forceinline__ ushort_t f2bf(float f) {
    unsigned u = __float_as_uint(f);
    unsigned r = (u + 0x7FFFu + ((u >> 16) & 1u)) >> 16;   // RNE
    return (ushort_t)r;
}

// ====================== bf16 conversion of concat(ue,ie) ===================
__global__ __launch_bounds__(256) void k_cvt(const float* __restrict__ ue,
                                             const float* __restrict__ ie,
                                             ushort_t* __restrict__ b0) {
    int i = blockIdx.x * blockDim.x + threadIdx.x;     // 8-float chunk id
    if (i >= TOT_F / 8) return;
    const float4* src = (i < USER_F4 / 2)
        ? reinterpret_cast<const float4*>(ue) + 2 * i
        : reinterpret_cast<const float4*>(ie) + 2 * i - USER_F4;
    float4 a = src[0], b = src[1];
    ushort_t o[8] = { f2bf(a.x), f2bf(a.y), f2bf(a.z), f2bf(a.w),
                      f2bf(b.x), f2bf(b.y), f2bf(b.z), f2bf(b.w) };
    reinterpret_cast<uint4*>(b0)[i] = *reinterpret_cast<uint4*>(o);
}

// ============================ CSR build ====================================

__global__ __launch_bounds__(256) void k_hist(const int* __restrict__ rows,
                                              int* __restrict__ cnt,
                                              int* __restrict__ loff) {
    int i = blockIdx.x * blockDim.x + threadIdx.x;
    if (i >= NNZ / 4) return;
    int4 r = reinterpret_cast<const int4*>(rows)[i];
    int4 o;
    o.x = atomicAdd(&cnt[r.x], 1);
    o.y = atomicAdd(&cnt[r.y], 1);
    o.z = atomicAdd(&cnt[r.z], 1);
    o.w = atomicAdd(&cnt[r.w], 1);
    reinterpret_cast<int4*>(loff)[i] = o;
}

__global__ __launch_bounds__(256) void k_block_sum(const int* __restrict__ cnt,
                                                   int* __restrict__ part) {
    __shared__ int lds[256];
    int b = blockIdx.x, t = threadIdx.x;
    int base = b * SCAN_CHUNK + t * 4;
    int s = 0;
#pragma unroll
    for (int k = 0; k < 4; ++k)
        if (base + k < NTOT) s += cnt[base + k];
    lds[t] = s;
    __syncthreads();
    for (int off = 128; off > 0; off >>= 1) {
        if (t < off) lds[t] += lds[t + off];
        __syncthreads();
    }
    if (t == 0) part[b] = lds[0];
}

// serial scan of partials; writes CSR sentinel and zero-pads ecv tail (32)
__global__ void k_scan_partials(int* part, int* rstart, long long* ecv) {
    if (blockIdx.x == 0 && threadIdx.x == 0) {
        int run = 0;
        for (int i = 0; i < NB_SCAN; ++i) {
            int p = part[i];
            part[i] = run;
            run += p;
        }
        rstart[NTOT] = NNZ;
        for (int i = 0; i < 32; ++i) ecv[NNZ + i] = 0;   // pad: off=0, val=0
    }
}

__global__ __launch_bounds__(256) void k_scan_block(const int* __restrict__ cnt,
                                                    const int* __restrict__ part,
                                                    int* __restrict__ rstart) {
    __shared__ int lds[256];
    int b = blockIdx.x, t = threadIdx.x;
    int base = b * SCAN_CHUNK + t * 4;
    int v0 = 0, v1 = 0, v2 = 0, v3 = 0;
    if (base + 0 < NTOT) v0 = cnt[base + 0];
    if (base + 1 < NTOT) v1 = cnt[base + 1];
    if (base + 2 < NTOT) v2 = cnt[base + 2];
    if (base + 3 < NTOT) v3 = cnt[base + 3];
    int s = v0 + v1 + v2 + v3;
    lds[t] = s;
    __syncthreads();
    for (int off = 1; off < 256; off <<= 1) {
        int x = (t >= off) ? lds[t - off] : 0;
        __syncthreads();
        lds[t] += x;
        __syncthreads();
    }
    int excl = lds[t] - s + part[b];
    int e0 = excl, e1 = e0 + v0, e2 = e1 + v1, e3 = e2 + v2;
    if (base + 0 < NTOT) rstart[base + 0] = e0;
    if (base + 1 < NTOT) rstart[base + 1] = e1;
    if (base + 2 < NTOT) rstart[base + 2] = e2;
    if (base + 3 < NTOT) rstart[base + 3] = e3;
}

// atomic-free permute: pos = rstart[row] + loff[edge]
// stores {col*128 (byte offset into bf16 table), val bits} per edge
__global__ __launch_bounds__(256) void k_permute(const float* __restrict__ vals,
                                                 const int* __restrict__ rows,
                                                 const int* __restrict__ cols,
                                                 const int* __restrict__ rstart,
                                                 const int* __restrict__ loff,
                                                 long long* __restrict__ ecv) {
    int i = blockIdx.x * blockDim.x + threadIdx.x;
    if (i >= NNZ / 4) return;
    int4   r  = reinterpret_cast<const int4*>(rows)[i];
    int4   c  = reinterpret_cast<const int4*>(cols)[i];
    float4 v  = reinterpret_cast<const float4*>(vals)[i];
    int4   lo = reinterpret_cast<const int4*>(loff)[i];
#define PUT(RR, LO, CC, VV)                                              \
    {                                                                    \
        int pos = rstart[RR] + (LO);                                     \
        ecv[pos] = ((long long)((unsigned)(CC) << 7) << 32) |            \
                   (unsigned)__float_as_int(VV);                         \
    }
    PUT(r.x, lo.x, c.x, v.x)
    PUT(r.y, lo.y, c.y, v.y)
    PUT(r.z, lo.z, c.z, v.z)
    PUT(r.w, lo.w, c.w, v.w)
#undef PUT
}

// ============================ SpMM (CSR, bf16 gather) ======================
// One wave per row. Lanes 0-31 process even chunk-slots, 32-63 odd; each lane
// covers 2 dims via one ushort2 gather. Next-chunk ecv prefetched.

template<int LAYER>
__global__ __launch_bounds__(256) void k_spmm(const int* __restrict__ rstart,
                                              const long long* __restrict__ ecv,
                                              const ushort_t* __restrict__ src,
                                              const float* __restrict__ ue,
                                              const float* __restrict__ ie,
                                              ushort_t* __restrict__ dstb,
                                              float* __restrict__ out) {
    int wid  = blockIdx.x * 4 + (threadIdx.x >> 6);   // row
    int lane = threadIdx.x & 63;
    if (wid >= NTOT) return;
    int start = rstart[wid];
    int end   = rstart[wid + 1];

    const int half = lane >> 5;          // which slot parity this lane handles
    const int d02  = (lane & 31) * 4;    // byte offset of dim pair within row

    float acc0 = 0.f, acc1 = 0.f;
    long long q = ecv[start + (lane & 15)];          // chunk: slot s in lane s
    for (int base = start; base < end; base += 16) {
        int rem = end - base;
        long long qn = q;
        if (rem > 16) qn = ecv[base + 16 + (lane & 15)];   // prefetch next
        int qlo = (int)(unsigned)(q & 0xffffffffu);
        int qhi = (int)(unsigned)((unsigned long long)q >> 32);
        int remh = rem - half;
#pragma unroll
        for (int j = 0; j < 8; ++j) {
            int slot = 2 * j + half;
            float v  = __int_as_float(__shfl(qlo, slot));
            unsigned off = (unsigned)__shfl(qhi, slot);
            v = (2 * j < remh) ? v : 0.f;
            unsigned u = *reinterpret_cast<const unsigned*>(
                             reinterpret_cast<const char*>(src) + (off + d02));
            acc0 += v * __uint_as_float(u << 16);
            acc1 += v * __uint_as_float(u & 0xffff0000u);
        }
        q = qn;
    }

    // combine the two edge-parity halves: lane l <-> lane l^32 hold same dims
    acc0 += __shfl_xor(acc0, 32);
    acc1 += __shfl_xor(acc1, 32);

    if (lane < 32) {
        size_t o = (size_t)wid * DIM + (size_t)lane * 2;
        unsigned pk = ((unsigned)f2bf(acc1) << 16) | (unsigned)f2bf(acc0);
        if (LAYER == 1) {
            const float* bsrc = (wid < N_USERS)
                ? ue + o : ie + (o - (size_t)N_USERS * DIM);
            float2 b2 = *reinterpret_cast<const float2*>(bsrc);
            __builtin_nontemporal_store(b2.x + acc0, out + o);
            __builtin_nontemporal_store(b2.y + acc1, out + o + 1);
            *reinterpret_cast<unsigned*>(dstb + o) = pk;
        } else if (LAYER == 2) {
            float2 prev = *reinterpret_cast<const float2*>(out + o);
            __builtin_nontemporal_store(prev.x + acc0, out + o);
            __builtin_nontemporal_store(prev.y + acc1, out + o + 1);
            *reinterpret_cast<unsigned*>(dstb + o) = pk;
        } else {
            float2 prev = *reinterpret_cast<const float2*>(out + o);
            __builtin_nontemporal_store((prev.x + acc0) * 0.25f, out + o);
            __builtin_nontemporal_store((prev.y + acc1) * 0.25f, out + o + 1);
        }
    }
}

// ===================== fallback (atomic path, small ws) ====================

template<bool FROM_INPUTS>
__global__ __launch_bounds__(256) void scatter_kernel(
        const float* __restrict__ vals, const int* __restrict__ rows,
        const int* __restrict__ cols, const float* __restrict__ src,
        const float* __restrict__ ue, const float* __restrict__ ie,
        float* __restrict__ dst) {
    const int e = blockIdx.x * (blockDim.x >> 4) + (threadIdx.x >> 4);
    const int lane = threadIdx.x & 15;
    if (e >= NNZ) return;
    const float v = vals[e];
    const int c = cols[e];
    const int r = rows[e];
    const float* s = FROM_INPUTS
        ? ((c < N_USERS) ? (ue + (size_t)c * DIM) : (ie + (size_t)(c - N_USERS) * DIM))
        : (src + (size_t)c * DIM);
    const float4 x = reinterpret_cast<const float4*>(s)[lane];
    float* d = dst + (size_t)r * DIM + (size_t)lane * 4;
    atomicAdd(d + 0, v * x.x); atomicAdd(d + 1, v * x.y);
    atomicAdd(d + 2, v * x.z); atomicAdd(d + 3, v * x.w);
}

__global__ __launch_bounds__(256) void acc1_kernel(
        const float* __restrict__ ue, const float* __restrict__ ie,
        const float* __restrict__ a, float* __restrict__ out) {
    int i = blockIdx.x * blockDim.x + threadIdx.x;
    if (i >= TOT_F4) return;
    float4 base = (i < USER_F4)
        ? reinterpret_cast<const float4*>(ue)[i]
        : reinterpret_cast<const float4*>(ie)[i - USER_F4];
    float4 av = reinterpret_cast<const float4*>(a)[i];
    reinterpret_cast<float4*>(out)[i] =
        make_float4(base.x + av.x, base.y + av.y, base.z + av.z, base.w + av.w);
}

__global__ __launch_bounds__(256) void add_zero_kernel(
        const float* __restrict__ b, float* __restrict__ out,
        float* __restrict__ z) {
    int i = blockIdx.x * blockDim.x + threadIdx.x;
    if (i >= TOT_F4) return;
    float4 bv = reinterpret_cast<const float4*>(b)[i];
    float4 ov = reinterpret_cast<float4*>(out)[i];
    reinterpret_cast<float4*>(out)[i] =
        make_float4(ov.x + bv.x, ov.y + bv.y, ov.z + bv.z, ov.w + bv.w);
    reinterpret_cast<float4*>(z)[i] = make_float4(0.f, 0.f, 0.f, 0.f);
}

__global__ __launch_bounds__(256) void final_kernel(
        const float* __restrict__ b, float* __restrict__ out) {
    int i = blockIdx.x * blockDim.x + threadIdx.x;
    if (i >= TOT_F4) return;
    float4 bv = reinterpret_cast<const float4*>(b)[i];
    float4 ov = reinterpret_cast<float4*>(out)[i];
    reinterpret_cast<float4*>(out)[i] =
        make_float4((ov.x + bv.x) * 0.25f, (ov.y + bv.y) * 0.25f,
                    (ov.z + bv.z) * 0.25f, (ov.w + bv.w) * 0.25f);
}

// ===========================================================================

extern "C" void kernel_launch(void* const* d_in, const int* in_sizes, int n_in,
                              void* d_out, int out_size, void* d_ws, size_t ws_size,
                              hipStream_t stream)
{
    const float* ue   = (const float*)d_in[0];
    const float* ie   = (const float*)d_in[1];
    const float* vals = (const float*)d_in[2];
    const int*   rows = (const int*)  d_in[3];
    const int*   cols = (const int*)  d_in[4];
    float* out = (float*)d_out;

    // bf16 tables: 300000*64*2 = 38,400,000 bytes each
    const size_t BBUF   = (size_t)TOT_F * 2;
    const size_t O_B1   = BBUF;
    const size_t O_B2   = 2 * BBUF;
    const size_t O_ECV  = 3 * BBUF;                        // 16B aligned
    const size_t O_LOFF = O_ECV + (size_t)(NNZ + 32) * 8;  // +pad, 16B aligned
    const size_t O_CNT  = O_LOFF + (size_t)NNZ * 4;
    const size_t O_RST  = O_CNT + (size_t)NTOT * 4;
    const size_t O_PART = O_RST + (size_t)(NTOT + 1) * 4;
    const size_t NEED   = O_PART + 4096;

    if (ws_size >= NEED) {
        ushort_t* b0     = (ushort_t*)d_ws;
        ushort_t* b1     = (ushort_t*)((char*)d_ws + O_B1);
        ushort_t* b2     = (ushort_t*)((char*)d_ws + O_B2);
        long long* ecv   = (long long*)((char*)d_ws + O_ECV);
        int*      loff   = (int*)((char*)d_ws + O_LOFF);
        int*      cnt    = (int*)((char*)d_ws + O_CNT);
        int*      rstart = (int*)((char*)d_ws + O_RST);
        int*      part   = (int*)((char*)d_ws + O_PART);

        const int eg4 = (NNZ / 4 + 255) / 256;
        const int cg  = (TOT_F / 8 + 255) / 256;
        const int sg  = (NTOT + 3) / 4;

        hipMemsetAsync(cnt, 0, (size_t)NTOT * 4, stream);
        k_cvt<<<cg, 256, 0, stream>>>(ue, ie, b0);
        k_hist<<<eg4, 256, 0, stream>>>(rows, cnt, loff);
        k_block_sum<<<NB_SCAN, 256, 0, stream>>>(cnt, part);
        k_scan_partials<<<1, 64, 0, stream>>>(part, rstart, ecv);
        k_scan_block<<<NB_SCAN, 256, 0, stream>>>(cnt, part, rstart);
        k_permute<<<eg4, 256, 0, stream>>>(vals, rows, cols, rstart, loff, ecv);

        k_spmm<1><<<sg, 256, 0, stream>>>(rstart, ecv, b0, ue, ie, b1, out);
        k_spmm<2><<<sg, 256, 0, stream>>>(rstart, ecv, b1, ue, ie, b2, out);
        k_spmm<3><<<sg, 256, 0, stream>>>(rstart, ecv, b2, ue, ie, nullptr, out);
    } else {
        const size_t BUF = (size_t)TOT_F * sizeof(float);
        float* ws0 = (float*)d_ws;
        float* ws1 = (float*)((char*)d_ws + BUF);
        const int eb = 256;
        const int eg2 = (TOT_F4 + eb - 1) / eb;
        const int sg2 = (NNZ + 15) / 16;
        hipMemsetAsync(ws0, 0, BUF, stream);
        hipMemsetAsync(ws1, 0, BUF, stream);
        scatter_kernel<true><<<sg2, 256, 0, stream>>>(vals, rows, cols,
                                                      nullptr, ue, ie, ws0);
        acc1_kernel<<<eg2, eb, 0, stream>>>(ue, ie, ws0, out);
        scatter_kernel<false><<<sg2, 256, 0, stream>>>(vals, rows, cols,
                                                       ws0, nullptr, nullptr, ws1);
        add_zero_kernel<<<eg2, eb, 0, stream>>>(ws1, out, ws0);
        scatter_kernel<false><<<sg2, 256, 0, stream>>>(vals, rows, cols,
                                                       ws1, nullptr, nullptr, ws0);
        final_kernel<<<eg2, eb, 0, stream>>>(ws0, out);
    }
}